// Round 17
// baseline (471.155 us; speedup 1.0000x reference)
//
#include <hip/hip_runtime.h>
#include <hip/hip_bf16.h>
#include <stdint.h>

#define M_DIM 4096
#define N_DIM 11008
#define K_DIM 4096

typedef float f32x4 __attribute__((ext_vector_type(4)));
typedef __bf16 bf16x8 __attribute__((ext_vector_type(8)));
typedef unsigned short u16x8 __attribute__((ext_vector_type(8)));
typedef unsigned short u16x4 __attribute__((ext_vector_type(4)));

typedef __attribute__((address_space(1))) const unsigned int guint;
typedef __attribute__((address_space(3))) unsigned int luint;
#define GLOAD_LDS16(g, l) \
    __builtin_amdgcn_global_load_lds((guint*)(g), (luint*)(l), 16, 0, 0)

#define WAIT_VM6() asm volatile("s_waitcnt vmcnt(6)" ::: "memory")
#define WAIT_VM0() asm volatile("s_waitcnt vmcnt(0)" ::: "memory")

__device__ __forceinline__ unsigned short f2bf(float f) {
    union { float f; unsigned u; } v; v.f = f;
    return (unsigned short)((v.u + 0x7FFFu + ((v.u >> 16) & 1u)) >> 16);
}

// ---------------- Pass 1 (fused): cvt FIRST, dequant LAST ----------------
// Dequant's Wt (90 MB, the GEMM's largest operand) is written LAST so it is
// hottest in L3 when the GEMM launches (r12->r13).  X is read once -> NT
// loads (r16: prep+gap 45 -> ~19us).
#define DQ_BLOCKS  ((N_DIM / 64) * (K_DIM / 256))   // 172*16 = 2752
#define CVT_BLOCKS 2048
#define CVT_TOTAL  ((size_t)M_DIM * K_DIM)          // 16.7M elems

__global__ void __launch_bounds__(256) prep_kernel(
    const float* __restrict__ X, const int* __restrict__ QW,
    const int* __restrict__ QZ, const float* __restrict__ SC,
    __hip_bfloat16* __restrict__ Xbf, __hip_bfloat16* __restrict__ Wt)
{
    const int bid = blockIdx.x;
    if (bid >= CVT_BLOCKS) {
        // ---- dequant: identical math/indexing to proven dequant_kernel ----
        const int db  = bid - CVT_BLOCKS;
        const int bx  = db % (N_DIM / 64);
        const int by  = db / (N_DIM / 64);
        const int n   = bx * 64 + (threadIdx.x & 63);
        const int k64 = by * 4 + (threadIdx.x >> 6);   // 64 k-values per thread
        const int g   = k64 >> 1;                      // group = k/128
        const int zp  = ((unsigned)QZ[g * (N_DIM / 8) + (n >> 3)]
                         >> ((n & 7) << 2)) & 15;
        const float sc = SC[g * N_DIM + n];
        const float zs = (float)zp * sc;
        unsigned qv[8];
        #pragma unroll
        for (int r = 0; r < 8; ++r)
            qv[r] = (unsigned)QW[(size_t)(k64 * 8 + r) * N_DIM + n];
        #pragma unroll
        for (int r = 0; r < 8; ++r) {
            bf16x8 h;
            #pragma unroll
            for (int j = 0; j < 8; ++j)
                h[j] = (__bf16)((float)((qv[r] >> (j * 4)) & 15u) * sc - zs);
            *reinterpret_cast<bf16x8*>(Wt + (size_t)n * K_DIM + k64 * 64 + r * 8) = h;
        }
    } else {
        // ---- cvt: grid-stride, 8 f32 -> 8 bf16 per thread-iter, NT loads ----
        const size_t nthreads = (size_t)CVT_BLOCKS * 256;
        size_t i = ((size_t)bid * 256 + threadIdx.x) * 8;
        const size_t stride = nthreads * 8;
        for (; i < CVT_TOTAL; i += stride) {
            f32x4 a = __builtin_nontemporal_load(
                reinterpret_cast<const f32x4*>(X + i));
            f32x4 b = __builtin_nontemporal_load(
                reinterpret_cast<const f32x4*>(X + i + 4));
            bf16x8 h;
            #pragma unroll
            for (int e = 0; e < 4; ++e) { h[e] = (__bf16)a[e]; h[e + 4] = (__bf16)b[e]; }
            *reinterpret_cast<bf16x8*>(Xbf + i) = h;
        }
    }
}

// ---------------- Pass 2: 256x128 bf16 GEMM, 2 blocks/CU -------------------
// Structural test: INTER-BLOCK overlap.  All ~50%-walled variants (r7-r14)
// ran 1 barrier-locked block/CU -> CU-wide serialization of MFMA and LDS-read
// windows (2480 vs 2300 SIMD-cyc/K-tile).  Here: 2 INDEPENDENT blocks/CU --
// while one drains at its barrier, the other's MFMAs fill the matrix pipe.
// Per block: 256 thr, 4 waves 2Mx2N of 128x64 (keeps the proven 42.7 FLOP/B
// LDS-read intensity; r15's 64x64 regression isolated intensity as critical),
// BK=32, 2-buffer LDS 2x24KB = 48KB (A 16KB @0, B 8KB @16384), r4-proven loop
// {WAIT_VM6; bar; compute; bar; stage(c+2)} (6 gloads/stage, 1 stage in
// flight across the barrier), r4's zero-conflict slot-XOR (slot^=(row>>1)&3;
// involution verified for 64-row chunks since chunk*32 = 0 mod 4), verified
// 16x16x32 frag/C layouts, NT epilogue stores (r16).
// launch_bounds(256,2): 2 waves/EU -> k = 2*4/(256/64) = 2 blocks/CU, VGPR
// cap 256 (need ~190: acc 128 + frags 32 + addr).  Grid 16Mx86N = 1376.
__global__ void __launch_bounds__(256, 2) gemm_bf16_kernel(
    const __hip_bfloat16* __restrict__ A,   // [4096][4096] (m,k)
    const __hip_bfloat16* __restrict__ Bt,  // [11008][4096] (n,k)
    const float* __restrict__ BIAS, float* __restrict__ OUT)
{
    __shared__ __align__(16) unsigned char lds[49152];  // 2 x 24KB

    const int tid  = threadIdx.x;
    const int wave = tid >> 6;
    const int lane = tid & 63;
    const int l15  = lane & 15;
    const int lhi  = lane >> 4;
    const int wr   = wave >> 1;   // 0..1 (M, 128-row strips)
    const int wc   = wave & 1;    // 0..1 (N, 64-col strips)

    // XCD-bijective swizzle: 1376 blocks = 8 XCDs x 172, M-fastest in chunk
    const int bid = blockIdx.x;
    const int swz = (bid & 7) * 172 + (bid >> 3);
    const int m0  = (swz & 15) * 256;
    const int n0  = (swz >> 4) * 128;

    // ---- staging geometry (r4-proven): per gload, thread t -> dest byte
    // t*16 in a 4KB 64-row chunk; row-in-chunk = t>>2, slot = t&3; source k
    // pre-swizzled slot ^ ((row>>1)&3) = (t&3) ^ ((t>>3)&3) for all chunks.
    const int arow = tid >> 2;                          // 0..63
    const int kof  = ((tid & 3) ^ ((tid >> 3) & 3)) * 8;
    const int t16  = tid * 16;
    const __hip_bfloat16* Asrc = A  + (size_t)(m0 + arow) * K_DIM + kof;
    const __hip_bfloat16* Bsrc = Bt + (size_t)(n0 + arow) * K_DIM + kof;

    // ---- fragment-read offsets: row*64 + ((lhi ^ ((l15>>1)&3))<<4) ----
    const int sws = (lhi ^ ((l15 >> 1) & 3)) << 4;
    int aoff[8], boff[4];
    #pragma unroll
    for (int fr = 0; fr < 8; ++fr)
        aoff[fr] = (wr * 128 + fr * 16 + l15) * 64 + sws;
    #pragma unroll
    for (int fc = 0; fc < 4; ++fc)
        boff[fc] = 16384 + (wc * 64 + fc * 16 + l15) * 64 + sws;

    f32x4 acc[8][4] = {};

    auto stage = [&](int c) {
        const int buf = (c & 1) * 24576;
        const size_t k = (size_t)c * 32;
        GLOAD_LDS16(Asrc + k,                        lds + buf + t16);
        GLOAD_LDS16(Asrc + k + (size_t)64  * K_DIM,  lds + buf + 4096  + t16);
        GLOAD_LDS16(Asrc + k + (size_t)128 * K_DIM,  lds + buf + 8192  + t16);
        GLOAD_LDS16(Asrc + k + (size_t)192 * K_DIM,  lds + buf + 12288 + t16);
        GLOAD_LDS16(Bsrc + k,                        lds + buf + 16384 + t16);
        GLOAD_LDS16(Bsrc + k + (size_t)64  * K_DIM,  lds + buf + 20480 + t16);
    };

    auto compute = [&](int c) {
        const int buf = (c & 1) * 24576;
        bf16x8 afr[4], bfr[4];
        #pragma unroll
        for (int fc = 0; fc < 4; ++fc)
            bfr[fc] = *reinterpret_cast<const bf16x8*>(lds + buf + boff[fc]);
        #pragma unroll
        for (int fr = 0; fr < 4; ++fr)
            afr[fr] = *reinterpret_cast<const bf16x8*>(lds + buf + aoff[fr]);
        __builtin_amdgcn_s_setprio(1);
        #pragma unroll
        for (int fr = 0; fr < 4; ++fr)
            #pragma unroll
            for (int fc = 0; fc < 4; ++fc)
                acc[fr][fc] = __builtin_amdgcn_mfma_f32_16x16x32_bf16(
                    afr[fr], bfr[fc], acc[fr][fc], 0, 0, 0);
        __builtin_amdgcn_s_setprio(0);
        #pragma unroll
        for (int fr = 0; fr < 4; ++fr)
            afr[fr] = *reinterpret_cast<const bf16x8*>(lds + buf + aoff[fr + 4]);
        __builtin_amdgcn_s_setprio(1);
        #pragma unroll
        for (int fr = 0; fr < 4; ++fr)
            #pragma unroll
            for (int fc = 0; fc < 4; ++fc)
                acc[fr + 4][fc] = __builtin_amdgcn_mfma_f32_16x16x32_bf16(
                    afr[fr], bfr[fc], acc[fr + 4][fc], 0, 0, 0);
        __builtin_amdgcn_s_setprio(0);
    };

    stage(0); stage(1);   // 12 loads in flight

    for (int c = 0; c < 126; ++c) {
        WAIT_VM6();                       // own stage(c) complete
        __builtin_amdgcn_s_barrier();     // all waves' stage(c) complete
        compute(c);
        __builtin_amdgcn_s_barrier();     // all waves done reading buf(c)
        stage(c + 2);                     // overwrite just-freed buffer
    }
    WAIT_VM6();                           // c = 126
    __builtin_amdgcn_s_barrier();
    compute(126);
    __builtin_amdgcn_s_barrier();
    WAIT_VM0();                           // c = 127
    __builtin_amdgcn_s_barrier();
    compute(127);

    // epilogue: OUT = acc + bias (non-temporal: written once, never re-read)
    #pragma unroll
    for (int fc = 0; fc < 4; ++fc) {
        const int n    = n0 + wc * 64 + fc * 16 + l15;
        const float bv = BIAS[n];
        #pragma unroll
        for (int fr = 0; fr < 8; ++fr) {
            const int mb = m0 + wr * 128 + fr * 16 + (lhi << 2);
            #pragma unroll
            for (int t = 0; t < 4; ++t)
                __builtin_nontemporal_store(acc[fr][fc][t] + bv,
                    &OUT[(size_t)(mb + t) * N_DIM + n]);
        }
    }
}

// ---------------- Fallback: round-1 fused kernel ----------------
__global__ void __launch_bounds__(256) gptq_gemm_kernel(
    const float* __restrict__ X, const int* __restrict__ QW,
    const int* __restrict__ QZ, const float* __restrict__ SC,
    const float* __restrict__ BIAS, float* __restrict__ OUT)
{
    __shared__ __align__(16) unsigned char slds[32768];
    const int tid  = threadIdx.x;
    const int n0   = blockIdx.x * 128;
    const int m0   = blockIdx.y * 128;
    const int wave = tid >> 6;
    const int lane = tid & 63;
    const int wm   = (wave >> 1) * 64;
    const int wn   = (wave & 1) * 64;
    const int l15  = lane & 15;
    const int lhi  = lane >> 4;
    const int arow  = tid >> 4;
    const int acol4 = (tid & 15) << 2;
    const int bnl   = tid & 127;
    const int brb   = tid >> 7;
    const int col   = n0 + bnl;

    f32x4 acc[4][4] = {};
    for (int kt = 0; kt < K_DIM / 64; ++kt) {
        const int k0 = kt * 64;
        #pragma unroll
        for (int r8 = 0; r8 < 8; ++r8) {
            const int row = (r8 << 4) + arow;
            f32x4 v = *reinterpret_cast<const f32x4*>(
                X + (size_t)(m0 + row) * K_DIM + (k0 + acol4));
            u16x4 h;
            #pragma unroll
            for (int e = 0; e < 4; ++e) h[e] = f2bf(v[e]);
            const int bo = row * 128 + ((acol4 << 1) ^ ((row & 7) << 4));
            *reinterpret_cast<u16x4*>(slds + bo) = h;
        }
        {
            const int g    = k0 >> 7;
            const int zp   = (((unsigned)QZ[g * (N_DIM / 8) + (col >> 3)])
                              >> ((col & 7) << 2)) & 15;
            const float sc = SC[g * N_DIM + col];
            const float zs = (float)zp * sc;
            #pragma unroll
            for (int rb = 0; rb < 4; ++rb) {
                const int rl = (rb << 1) + brb;
                const unsigned qw =
                    (unsigned)QW[(size_t)((k0 >> 3) + rl) * N_DIM + col];
                u16x8 h;
                #pragma unroll
                for (int j = 0; j < 8; ++j) {
                    float w = (float)((qw >> (j << 2)) & 15u) * sc - zs;
                    h[j] = f2bf(w);
                }
                const int bo = 16384 + bnl * 128 + ((rl << 4) ^ ((bnl & 7) << 4));
                *reinterpret_cast<u16x8*>(slds + bo) = h;
            }
        }
        __syncthreads();
        #pragma unroll
        for (int kk = 0; kk < 2; ++kk) {
            bf16x8 afr[4], bfr[4];
            #pragma unroll
            for (int i = 0; i < 4; ++i) {
                const int row = wm + (i << 4) + l15;
                afr[i] = *reinterpret_cast<const bf16x8*>(
                    slds + row * 128 + (((kk << 6) + (lhi << 4)) ^ ((row & 7) << 4)));
            }
            #pragma unroll
            for (int j = 0; j < 4; ++j) {
                const int n = wn + (j << 4) + l15;
                bfr[j] = *reinterpret_cast<const bf16x8*>(
                    slds + 16384 + n * 128 + (((kk << 6) + (lhi << 4)) ^ ((n & 7) << 4)));
            }
            #pragma unroll
            for (int i = 0; i < 4; ++i)
                #pragma unroll
                for (int j = 0; j < 4; ++j)
                    acc[i][j] = __builtin_amdgcn_mfma_f32_16x16x32_bf16(
                        afr[i], bfr[j], acc[i][j], 0, 0, 0);
        }
        __syncthreads();
    }
    #pragma unroll
    for (int j = 0; j < 4; ++j) {
        const int n    = n0 + wn + (j << 4) + l15;
        const float bv = BIAS[n];
        #pragma unroll
        for (int i = 0; i < 4; ++i) {
            const int mb = m0 + wm + (i << 4) + (lhi << 2);
            #pragma unroll
            for (int t = 0; t < 4; ++t)
                OUT[(size_t)(mb + t) * N_DIM + n] = acc[i][j][t] + bv;
        }
    }
}

extern "C" void kernel_launch(void* const* d_in, const int* in_sizes, int n_in,
                              void* d_out, int out_size, void* d_ws, size_t ws_size,
                              hipStream_t stream) {
    const float* X  = (const float*)d_in[0];
    const int*   QW = (const int*)d_in[1];
    const int*   QZ = (const int*)d_in[2];
    const float* SC = (const float*)d_in[3];
    const float* BI = (const float*)d_in[4];
    float*      OUT = (float*)d_out;

    const size_t xbf_bytes = (size_t)M_DIM * K_DIM * 2;
    const size_t wt_bytes  = (size_t)N_DIM * K_DIM * 2;

    if (ws_size >= xbf_bytes + wt_bytes) {
        __hip_bfloat16* Xbf = (__hip_bfloat16*)d_ws;
        __hip_bfloat16* Wt  = (__hip_bfloat16*)((char*)d_ws + xbf_bytes);

        prep_kernel<<<DQ_BLOCKS + CVT_BLOCKS, 256, 0, stream>>>(
            X, QW, QZ, SC, Xbf, Wt);
        gemm_bf16_kernel<<<dim3((M_DIM / 256) * (N_DIM / 128)), 256, 0, stream>>>(
            Xbf, Wt, BI, OUT);
    } else {
        gptq_gemm_kernel<<<dim3(N_DIM / 128, M_DIM / 128), 256, 0, stream>>>(
            X, QW, QZ, SC, BI, OUT);
    }
}

// Round 18
// 397.764 us; speedup vs baseline: 1.1845x; 1.1845x over previous
//
#include <hip/hip_runtime.h>
#include <hip/hip_bf16.h>
#include <stdint.h>

#define M_DIM 4096
#define N_DIM 11008
#define K_DIM 4096

typedef float f32x4 __attribute__((ext_vector_type(4)));
typedef __bf16 bf16x8 __attribute__((ext_vector_type(8)));
typedef unsigned short u16x8 __attribute__((ext_vector_type(8)));
typedef unsigned short u16x4 __attribute__((ext_vector_type(4)));

typedef __attribute__((address_space(1))) const unsigned int guint;
typedef __attribute__((address_space(3))) unsigned int luint;
#define GLOAD_LDS16(g, l) \
    __builtin_amdgcn_global_load_lds((guint*)(g), (luint*)(l), 16, 0, 0)

#define WAIT_VM4() asm volatile("s_waitcnt vmcnt(4)" ::: "memory")
#define WAIT_VM0() asm volatile("s_waitcnt vmcnt(0)" ::: "memory")

__device__ __forceinline__ unsigned short f2bf(float f) {
    union { float f; unsigned u; } v; v.f = f;
    return (unsigned short)((v.u + 0x7FFFu + ((v.u >> 16) & 1u)) >> 16);
}

// ---------------- Pass 1 (fused): cvt FIRST, dequant LAST ----------------
// Dequant's Wt (90 MB, the GEMM's largest operand) is written LAST so it is
// hottest in L3 when the GEMM launches (r12->r13).  X (100 MB) and QW
// (22.5 MB) are each read exactly once -> non-temporal loads (r16: X NT cut
// prep+gap 45 -> ~19us; QW NT keeps L2/L3 free for the Wt write stream).
#define DQ_BLOCKS  ((N_DIM / 64) * (K_DIM / 256))   // 172*16 = 2752
#define CVT_BLOCKS 2048
#define CVT_TOTAL  ((size_t)M_DIM * K_DIM)          // 16.7M elems

__global__ void __launch_bounds__(256) prep_kernel(
    const float* __restrict__ X, const int* __restrict__ QW,
    const int* __restrict__ QZ, const float* __restrict__ SC,
    __hip_bfloat16* __restrict__ Xbf, __hip_bfloat16* __restrict__ Wt)
{
    const int bid = blockIdx.x;
    if (bid >= CVT_BLOCKS) {
        // ---- dequant: identical math/indexing to proven dequant_kernel ----
        const int db  = bid - CVT_BLOCKS;
        const int bx  = db % (N_DIM / 64);
        const int by  = db / (N_DIM / 64);
        const int n   = bx * 64 + (threadIdx.x & 63);
        const int k64 = by * 4 + (threadIdx.x >> 6);   // 64 k-values per thread
        const int g   = k64 >> 1;                      // group = k/128
        const int zp  = ((unsigned)QZ[g * (N_DIM / 8) + (n >> 3)]
                         >> ((n & 7) << 2)) & 15;
        const float sc = SC[g * N_DIM + n];
        const float zs = (float)zp * sc;
        unsigned qv[8];
        #pragma unroll
        for (int r = 0; r < 8; ++r)
            qv[r] = (unsigned)__builtin_nontemporal_load(
                QW + (size_t)(k64 * 8 + r) * N_DIM + n);
        #pragma unroll
        for (int r = 0; r < 8; ++r) {
            bf16x8 h;
            #pragma unroll
            for (int j = 0; j < 8; ++j)
                h[j] = (__bf16)((float)((qv[r] >> (j * 4)) & 15u) * sc - zs);
            *reinterpret_cast<bf16x8*>(Wt + (size_t)n * K_DIM + k64 * 64 + r * 8) = h;
        }
    } else {
        // ---- cvt: grid-stride, 8 f32 -> 8 bf16 per thread-iter, NT loads ----
        const size_t nthreads = (size_t)CVT_BLOCKS * 256;
        size_t i = ((size_t)bid * 256 + threadIdx.x) * 8;
        const size_t stride = nthreads * 8;
        for (; i < CVT_TOTAL; i += stride) {
            f32x4 a = __builtin_nontemporal_load(
                reinterpret_cast<const f32x4*>(X + i));
            f32x4 b = __builtin_nontemporal_load(
                reinterpret_cast<const f32x4*>(X + i + 4));
            bf16x8 h;
            #pragma unroll
            for (int e = 0; e < 4; ++e) { h[e] = (__bf16)a[e]; h[e + 4] = (__bf16)b[e]; }
            *reinterpret_cast<bf16x8*>(Xbf + i) = h;
        }
    }
}

// ---------------- Pass 2: 256x256 bf16 GEMM, 2-barrier K-tile --------------
// FINAL structure (r16 best: total 378us, GEMM ~359us, MfmaUtil ~47.5, 0 bank
// conflicts, FETCH ~460MB).  512 thr, 8 waves 2Mx4N (128x64/wave), BK=64,
// 2-buffer LDS (2x64KB), K-split 16KB halves (A-kk0 @0, A-kk1 @16384,
// B-kk0 @32768, B-kk1 @49152), 4 phases/K-tile, 2 barriers/K-tile, counted
// vmcnt(4), zero-conflict XOR slot-swizzle via pre-swizzled gload source,
// NT epilogue stores.  Wait ledger (per-wave in-order queue, 2 loads/stage):
//   enter tile c: [A1(c),B1(c)]
//   ph0 +A0(c+1), ph1 +B0(c+1) -> vmcnt(4) retires A1,B1(c) -> BARRIER
//   ph2 +A1(c+1), ph3 +B1(c+1) -> vmcnt(4) retires A0,B0(c+1) -> BARRIER
// Exhausted-variant history (all isolated, all <= this): r7 +sched_barrier
// -9%; r9 32x32-frag bank conflicts; r10 burst staging -20%; r11 +post-MFMA
// barrier -7%; r15 128x256 work-stealing -15%; r17 2-blocks/CU 256x128
// -20% (FETCH 460MB -> 1.24GB, locality collapse).  launch_bounds (512,2):
// (512,4) spills the 128-reg acc (r5).
__global__ void __launch_bounds__(512, 2) gemm_bf16_kernel(
    const __hip_bfloat16* __restrict__ A,   // [4096][4096] (m,k)
    const __hip_bfloat16* __restrict__ Bt,  // [11008][4096] (n,k)
    const float* __restrict__ BIAS, float* __restrict__ OUT)
{
    extern __shared__ unsigned char lds[];  // 131072

    const int tid  = threadIdx.x;
    const int wave = tid >> 6;
    const int lane = tid & 63;
    const int l15  = lane & 15;
    const int lhi  = lane >> 4;
    const int wr   = wave >> 2;   // 0..1 (M, 128-row strips)
    const int wc   = wave & 3;    // 0..3 (N, 64-col strips)

    // XCD-bijective swizzle: 688 blocks = 8 XCDs x 86, M-fastest within chunk
    const int bid = blockIdx.x;
    const int swz = (bid & 7) * 86 + (bid >> 3);
    const int m0  = (swz & 15) * 256;
    const int n0  = (swz >> 4) * 256;

    // ---- staging geometry ----
    const int pp  = tid >> 3;
    const int so  = (tid & 7) ^ (pp & 7);
    const int grow = pp * 2 + (so >> 2);          // 0..127 (+128 for 2nd gload)
    const int klo  = (so & 3) * 8;                // 0/8/16/24
    const __hip_bfloat16* Asrc = A  + (size_t)(m0 + grow) * K_DIM + klo;
    const __hip_bfloat16* Bsrc = Bt + (size_t)(n0 + grow) * K_DIM + klo;
    const int t16 = tid * 16;

    // ---- fragment-read offsets ----
    const int sws   = (((l15 & 1) << 2) | lhi) ^ ((l15 >> 1) & 7);
    const int lbase = (l15 >> 1) * 128 + sws * 16;
    int aoff[8], boff[4];
    #pragma unroll
    for (int fr = 0; fr < 8; ++fr)
        aoff[fr] = (wr * 128 + fr * 16) * 64 + lbase;
    #pragma unroll
    for (int fc = 0; fc < 4; ++fc)
        boff[fc] = (wc * 64 + fc * 16) * 64 + lbase;

    f32x4 acc[8][4] = {};

    auto stA0 = [&](int c) {
        const int sb = (c & 1) * 65536; const size_t k = (size_t)c * 64;
        GLOAD_LDS16(Asrc + k,                        lds + sb + t16);
        GLOAD_LDS16(Asrc + k + (size_t)128 * K_DIM,  lds + sb + 8192 + t16);
    };
    auto stB0 = [&](int c) {
        const int sb = (c & 1) * 65536; const size_t k = (size_t)c * 64;
        GLOAD_LDS16(Bsrc + k,                        lds + sb + 32768 + t16);
        GLOAD_LDS16(Bsrc + k + (size_t)128 * K_DIM,  lds + sb + 32768 + 8192 + t16);
    };
    auto stA1 = [&](int c) {
        const int sb = (c & 1) * 65536; const size_t k = (size_t)c * 64 + 32;
        GLOAD_LDS16(Asrc + k,                        lds + sb + 16384 + t16);
        GLOAD_LDS16(Asrc + k + (size_t)128 * K_DIM,  lds + sb + 16384 + 8192 + t16);
    };
    auto stB1 = [&](int c) {
        const int sb = (c & 1) * 65536; const size_t k = (size_t)c * 64 + 32;
        GLOAD_LDS16(Bsrc + k,                        lds + sb + 49152 + t16);
        GLOAD_LDS16(Bsrc + k + (size_t)128 * K_DIM,  lds + sb + 49152 + 8192 + t16);
    };

    // one K-tile = 4 phases, 2 barriers (after ph1 and after ph3)
    auto tile = [&](int c, bool st, bool tail) {
        const int buf = (c & 1) * 65536;
        bf16x8 afr[4], bfr[4];
        // ---- ph0: kk0, fr0-3 ----
        #pragma unroll
        for (int fc = 0; fc < 4; ++fc)
            bfr[fc] = *reinterpret_cast<const bf16x8*>(lds + buf + 32768 + boff[fc]);
        #pragma unroll
        for (int fr = 0; fr < 4; ++fr)
            afr[fr] = *reinterpret_cast<const bf16x8*>(lds + buf + aoff[fr]);
        if (st) stA0(c + 1);
        __builtin_amdgcn_s_setprio(1);
        #pragma unroll
        for (int fr = 0; fr < 4; ++fr)
            #pragma unroll
            for (int fc = 0; fc < 4; ++fc)
                acc[fr][fc] = __builtin_amdgcn_mfma_f32_16x16x32_bf16(
                    afr[fr], bfr[fc], acc[fr][fc], 0, 0, 0);
        __builtin_amdgcn_s_setprio(0);
        // ---- ph1: kk0, fr4-7 (bfr held; no barrier before) ----
        #pragma unroll
        for (int fr = 0; fr < 4; ++fr)
            afr[fr] = *reinterpret_cast<const bf16x8*>(lds + buf + aoff[fr + 4]);
        if (st) stB0(c + 1);
        __builtin_amdgcn_s_setprio(1);
        #pragma unroll
        for (int fr = 0; fr < 4; ++fr)
            #pragma unroll
            for (int fc = 0; fc < 4; ++fc)
                acc[fr + 4][fc] = __builtin_amdgcn_mfma_f32_16x16x32_bf16(
                    afr[fr], bfr[fc], acc[fr + 4][fc], 0, 0, 0);
        __builtin_amdgcn_s_setprio(0);
        // sync: retire A1,B1(c) (own loads) + cross-wave visibility
        if (tail) { WAIT_VM0(); } else { WAIT_VM4(); }
        __builtin_amdgcn_s_barrier();
        // ---- ph2: kk1, fr0-3 ----
        #pragma unroll
        for (int fc = 0; fc < 4; ++fc)
            bfr[fc] = *reinterpret_cast<const bf16x8*>(lds + buf + 49152 + boff[fc]);
        #pragma unroll
        for (int fr = 0; fr < 4; ++fr)
            afr[fr] = *reinterpret_cast<const bf16x8*>(lds + buf + 16384 + aoff[fr]);
        if (st) stA1(c + 1);
        __builtin_amdgcn_s_setprio(1);
        #pragma unroll
        for (int fr = 0; fr < 4; ++fr)
            #pragma unroll
            for (int fc = 0; fc < 4; ++fc)
                acc[fr][fc] = __builtin_amdgcn_mfma_f32_16x16x32_bf16(
                    afr[fr], bfr[fc], acc[fr][fc], 0, 0, 0);
        __builtin_amdgcn_s_setprio(0);
        // ---- ph3: kk1, fr4-7 (no barrier before) ----
        #pragma unroll
        for (int fr = 0; fr < 4; ++fr)
            afr[fr] = *reinterpret_cast<const bf16x8*>(lds + buf + 16384 + aoff[fr + 4]);
        if (st) stB1(c + 1);
        __builtin_amdgcn_s_setprio(1);
        #pragma unroll
        for (int fr = 0; fr < 4; ++fr)
            #pragma unroll
            for (int fc = 0; fc < 4; ++fc)
                acc[fr + 4][fc] = __builtin_amdgcn_mfma_f32_16x16x32_bf16(
                    afr[fr], bfr[fc], acc[fr + 4][fc], 0, 0, 0);
        __builtin_amdgcn_s_setprio(0);
        // sync: retire A0,B0(c+1) + cross-wave visibility (skip at tail)
        if (!tail) {
            WAIT_VM4();
            __builtin_amdgcn_s_barrier();
        }
    };

    // prologue: stage tile 0; retire front halves (back stays in flight)
    stA0(0); stB0(0); stA1(0); stB1(0);
    WAIT_VM4();
    __builtin_amdgcn_s_barrier();

    for (int c = 0; c <= 62; ++c)
        tile(c, true, false);
    tile(63, false, true);

    // epilogue: OUT = acc + bias (non-temporal: written once, never re-read)
    #pragma unroll
    for (int fc = 0; fc < 4; ++fc) {
        const int n    = n0 + wc * 64 + fc * 16 + l15;
        const float bv = BIAS[n];
        #pragma unroll
        for (int fr = 0; fr < 8; ++fr) {
            const int mb = m0 + wr * 128 + fr * 16 + (lhi << 2);
            #pragma unroll
            for (int t = 0; t < 4; ++t)
                __builtin_nontemporal_store(acc[fr][fc][t] + bv,
                    &OUT[(size_t)(mb + t) * N_DIM + n]);
        }
    }
}

// ---------------- Fallback: round-1 fused kernel ----------------
__global__ void __launch_bounds__(256) gptq_gemm_kernel(
    const float* __restrict__ X, const int* __restrict__ QW,
    const int* __restrict__ QZ, const float* __restrict__ SC,
    const float* __restrict__ BIAS, float* __restrict__ OUT)
{
    __shared__ __align__(16) unsigned char slds[32768];
    const int tid  = threadIdx.x;
    const int n0   = blockIdx.x * 128;
    const int m0   = blockIdx.y * 128;
    const int wave = tid >> 6;
    const int lane = tid & 63;
    const int wm   = (wave >> 1) * 64;
    const int wn   = (wave & 1) * 64;
    const int l15  = lane & 15;
    const int lhi  = lane >> 4;
    const int arow  = tid >> 4;
    const int acol4 = (tid & 15) << 2;
    const int bnl   = tid & 127;
    const int brb   = tid >> 7;
    const int col   = n0 + bnl;

    f32x4 acc[4][4] = {};
    for (int kt = 0; kt < K_DIM / 64; ++kt) {
        const int k0 = kt * 64;
        #pragma unroll
        for (int r8 = 0; r8 < 8; ++r8) {
            const int row = (r8 << 4) + arow;
            f32x4 v = *reinterpret_cast<const f32x4*>(
                X + (size_t)(m0 + row) * K_DIM + (k0 + acol4));
            u16x4 h;
            #pragma unroll
            for (int e = 0; e < 4; ++e) h[e] = f2bf(v[e]);
            const int bo = row * 128 + ((acol4 << 1) ^ ((row & 7) << 4));
            *reinterpret_cast<u16x4*>(slds + bo) = h;
        }
        {
            const int g    = k0 >> 7;
            const int zp   = (((unsigned)QZ[g * (N_DIM / 8) + (col >> 3)])
                              >> ((col & 7) << 2)) & 15;
            const float sc = SC[g * N_DIM + col];
            const float zs = (float)zp * sc;
            #pragma unroll
            for (int rb = 0; rb < 4; ++rb) {
                const int rl = (rb << 1) + brb;
                const unsigned qw =
                    (unsigned)QW[(size_t)((k0 >> 3) + rl) * N_DIM + col];
                u16x8 h;
                #pragma unroll
                for (int j = 0; j < 8; ++j) {
                    float w = (float)((qw >> (j << 2)) & 15u) * sc - zs;
                    h[j] = f2bf(w);
                }
                const int bo = 16384 + bnl * 128 + ((rl << 4) ^ ((bnl & 7) << 4));
                *reinterpret_cast<u16x8*>(slds + bo) = h;
            }
        }
        __syncthreads();
        #pragma unroll
        for (int kk = 0; kk < 2; ++kk) {
            bf16x8 afr[4], bfr[4];
            #pragma unroll
            for (int i = 0; i < 4; ++i) {
                const int row = wm + (i << 4) + l15;
                afr[i] = *reinterpret_cast<const bf16x8*>(
                    slds + row * 128 + (((kk << 6) + (lhi << 4)) ^ ((row & 7) << 4)));
            }
            #pragma unroll
            for (int j = 0; j < 4; ++j) {
                const int n = wn + (j << 4) + l15;
                bfr[j] = *reinterpret_cast<const bf16x8*>(
                    slds + 16384 + n * 128 + (((kk << 6) + (lhi << 4)) ^ ((n & 7) << 4)));
            }
            #pragma unroll
            for (int i = 0; i < 4; ++i)
                #pragma unroll
                for (int j = 0; j < 4; ++j)
                    acc[i][j] = __builtin_amdgcn_mfma_f32_16x16x32_bf16(
                        afr[i], bfr[j], acc[i][j], 0, 0, 0);
        }
        __syncthreads();
    }
    #pragma unroll
    for (int j = 0; j < 4; ++j) {
        const int n    = n0 + wn + (j << 4) + l15;
        const float bv = BIAS[n];
        #pragma unroll
        for (int i = 0; i < 4; ++i) {
            const int mb = m0 + wm + (i << 4) + (lhi << 2);
            #pragma unroll
            for (int t = 0; t < 4; ++t)
                OUT[(size_t)(mb + t) * N_DIM + n] = acc[i][j][t] + bv;
        }
    }
}

extern "C" void kernel_launch(void* const* d_in, const int* in_sizes, int n_in,
                              void* d_out, int out_size, void* d_ws, size_t ws_size,
                              hipStream_t stream) {
    const float* X  = (const float*)d_in[0];
    const int*   QW = (const int*)d_in[1];
    const int*   QZ = (const int*)d_in[2];
    const float* SC = (const float*)d_in[3];
    const float* BI = (const float*)d_in[4];
    float*      OUT = (float*)d_out;

    const size_t xbf_bytes = (size_t)M_DIM * K_DIM * 2;
    const size_t wt_bytes  = (size_t)N_DIM * K_DIM * 2;

    if (ws_size >= xbf_bytes + wt_bytes) {
        __hip_bfloat16* Xbf = (__hip_bfloat16*)d_ws;
        __hip_bfloat16* Wt  = (__hip_bfloat16*)((char*)d_ws + xbf_bytes);

        prep_kernel<<<DQ_BLOCKS + CVT_BLOCKS, 256, 0, stream>>>(
            X, QW, QZ, SC, Xbf, Wt);
        gemm_bf16_kernel<<<dim3((M_DIM / 256) * (N_DIM / 256)), 512, 131072, stream>>>(
            Xbf, Wt, BI, OUT);
    } else {
        gptq_gemm_kernel<<<dim3(N_DIM / 128, M_DIM / 128), 256, 0, stream>>>(
            X, QW, QZ, SC, BI, OUT);
    }
}

// Round 19
// 378.302 us; speedup vs baseline: 1.2454x; 1.0514x over previous
//
#include <hip/hip_runtime.h>
#include <hip/hip_bf16.h>
#include <stdint.h>

#define M_DIM 4096
#define N_DIM 11008
#define K_DIM 4096

typedef float f32x4 __attribute__((ext_vector_type(4)));
typedef __bf16 bf16x8 __attribute__((ext_vector_type(8)));
typedef unsigned short u16x8 __attribute__((ext_vector_type(8)));
typedef unsigned short u16x4 __attribute__((ext_vector_type(4)));

typedef __attribute__((address_space(1))) const unsigned int guint;
typedef __attribute__((address_space(3))) unsigned int luint;
#define GLOAD_LDS16(g, l) \
    __builtin_amdgcn_global_load_lds((guint*)(g), (luint*)(l), 16, 0, 0)

#define WAIT_VM4() asm volatile("s_waitcnt vmcnt(4)" ::: "memory")
#define WAIT_VM0() asm volatile("s_waitcnt vmcnt(0)" ::: "memory")

__device__ __forceinline__ unsigned short f2bf(float f) {
    union { float f; unsigned u; } v; v.f = f;
    return (unsigned short)((v.u + 0x7FFFu + ((v.u >> 16) & 1u)) >> 16);
}

// ---------------- Pass 1 (fused): cvt FIRST, dequant LAST ----------------
// Dequant's Wt (90 MB, the GEMM's largest operand) is written LAST so it is
// hottest in L3 when the GEMM launches (r12->r13).  X is read once -> NT
// loads (r16: prep+gap 45 -> ~19us).  QW keeps NORMAL loads: r18 showed NT
// on QW costs ~20us (neighboring dequant blocks share QW lines via L2).
#define DQ_BLOCKS  ((N_DIM / 64) * (K_DIM / 256))   // 172*16 = 2752
#define CVT_BLOCKS 2048
#define CVT_TOTAL  ((size_t)M_DIM * K_DIM)          // 16.7M elems

__global__ void __launch_bounds__(256) prep_kernel(
    const float* __restrict__ X, const int* __restrict__ QW,
    const int* __restrict__ QZ, const float* __restrict__ SC,
    __hip_bfloat16* __restrict__ Xbf, __hip_bfloat16* __restrict__ Wt)
{
    const int bid = blockIdx.x;
    if (bid >= CVT_BLOCKS) {
        // ---- dequant: identical math/indexing to proven dequant_kernel ----
        const int db  = bid - CVT_BLOCKS;
        const int bx  = db % (N_DIM / 64);
        const int by  = db / (N_DIM / 64);
        const int n   = bx * 64 + (threadIdx.x & 63);
        const int k64 = by * 4 + (threadIdx.x >> 6);   // 64 k-values per thread
        const int g   = k64 >> 1;                      // group = k/128
        const int zp  = ((unsigned)QZ[g * (N_DIM / 8) + (n >> 3)]
                         >> ((n & 7) << 2)) & 15;
        const float sc = SC[g * N_DIM + n];
        const float zs = (float)zp * sc;
        unsigned qv[8];
        #pragma unroll
        for (int r = 0; r < 8; ++r)
            qv[r] = (unsigned)QW[(size_t)(k64 * 8 + r) * N_DIM + n];
        #pragma unroll
        for (int r = 0; r < 8; ++r) {
            bf16x8 h;
            #pragma unroll
            for (int j = 0; j < 8; ++j)
                h[j] = (__bf16)((float)((qv[r] >> (j * 4)) & 15u) * sc - zs);
            *reinterpret_cast<bf16x8*>(Wt + (size_t)n * K_DIM + k64 * 64 + r * 8) = h;
        }
    } else {
        // ---- cvt: grid-stride, 8 f32 -> 8 bf16 per thread-iter, NT loads ----
        const size_t nthreads = (size_t)CVT_BLOCKS * 256;
        size_t i = ((size_t)bid * 256 + threadIdx.x) * 8;
        const size_t stride = nthreads * 8;
        for (; i < CVT_TOTAL; i += stride) {
            f32x4 a = __builtin_nontemporal_load(
                reinterpret_cast<const f32x4*>(X + i));
            f32x4 b = __builtin_nontemporal_load(
                reinterpret_cast<const f32x4*>(X + i + 4));
            bf16x8 h;
            #pragma unroll
            for (int e = 0; e < 4; ++e) { h[e] = (__bf16)a[e]; h[e + 4] = (__bf16)b[e]; }
            *reinterpret_cast<bf16x8*>(Xbf + i) = h;
        }
    }
}

// ---------------- Pass 2: 256x256 bf16 GEMM, 2-barrier K-tile --------------
// FINAL structure (r16 best: total 378us, GEMM ~359us, MfmaUtil ~48, 0 bank
// conflicts, FETCH ~460MB).  512 thr, 8 waves 2Mx4N (128x64/wave), BK=64,
// 2-buffer LDS (2x64KB), K-split 16KB halves (A-kk0 @0, A-kk1 @16384,
// B-kk0 @32768, B-kk1 @49152), 4 phases/K-tile, 2 barriers/K-tile, counted
// vmcnt(4), zero-conflict XOR slot-swizzle via pre-swizzled gload source,
// NT epilogue stores.  Wait ledger (per-wave in-order queue, 2 loads/stage):
//   enter tile c: [A1(c),B1(c)]
//   ph0 +A0(c+1), ph1 +B0(c+1) -> vmcnt(4) retires A1,B1(c) -> BARRIER
//   ph2 +A1(c+1), ph3 +B1(c+1) -> vmcnt(4) retires A0,B0(c+1) -> BARRIER
// Exhausted-variant history (all isolated, all <= this): r7 +sched_barrier
// -9%; r9 32x32-frag bank conflicts; r10 burst staging -20%; r11 +post-MFMA
// barrier -7%; r15 128x256 work-stealing -15%; r17 2-blocks/CU 256x128
// -20% (FETCH 460MB -> 1.24GB); r18 NT-QW -5% total.  launch_bounds (512,2):
// (512,4) spills the 128-reg acc (r5).
__global__ void __launch_bounds__(512, 2) gemm_bf16_kernel(
    const __hip_bfloat16* __restrict__ A,   // [4096][4096] (m,k)
    const __hip_bfloat16* __restrict__ Bt,  // [11008][4096] (n,k)
    const float* __restrict__ BIAS, float* __restrict__ OUT)
{
    extern __shared__ unsigned char lds[];  // 131072

    const int tid  = threadIdx.x;
    const int wave = tid >> 6;
    const int lane = tid & 63;
    const int l15  = lane & 15;
    const int lhi  = lane >> 4;
    const int wr   = wave >> 2;   // 0..1 (M, 128-row strips)
    const int wc   = wave & 3;    // 0..3 (N, 64-col strips)

    // XCD-bijective swizzle: 688 blocks = 8 XCDs x 86, M-fastest within chunk
    const int bid = blockIdx.x;
    const int swz = (bid & 7) * 86 + (bid >> 3);
    const int m0  = (swz & 15) * 256;
    const int n0  = (swz >> 4) * 256;

    // ---- staging geometry ----
    const int pp  = tid >> 3;
    const int so  = (tid & 7) ^ (pp & 7);
    const int grow = pp * 2 + (so >> 2);          // 0..127 (+128 for 2nd gload)
    const int klo  = (so & 3) * 8;                // 0/8/16/24
    const __hip_bfloat16* Asrc = A  + (size_t)(m0 + grow) * K_DIM + klo;
    const __hip_bfloat16* Bsrc = Bt + (size_t)(n0 + grow) * K_DIM + klo;
    const int t16 = tid * 16;

    // ---- fragment-read offsets ----
    const int sws   = (((l15 & 1) << 2) | lhi) ^ ((l15 >> 1) & 7);
    const int lbase = (l15 >> 1) * 128 + sws * 16;
    int aoff[8], boff[4];
    #pragma unroll
    for (int fr = 0; fr < 8; ++fr)
        aoff[fr] = (wr * 128 + fr * 16) * 64 + lbase;
    #pragma unroll
    for (int fc = 0; fc < 4; ++fc)
        boff[fc] = (wc * 64 + fc * 16) * 64 + lbase;

    f32x4 acc[8][4] = {};

    auto stA0 = [&](int c) {
        const int sb = (c & 1) * 65536; const size_t k = (size_t)c * 64;
        GLOAD_LDS16(Asrc + k,                        lds + sb + t16);
        GLOAD_LDS16(Asrc + k + (size_t)128 * K_DIM,  lds + sb + 8192 + t16);
    };
    auto stB0 = [&](int c) {
        const int sb = (c & 1) * 65536; const size_t k = (size_t)c * 64;
        GLOAD_LDS16(Bsrc + k,                        lds + sb + 32768 + t16);
        GLOAD_LDS16(Bsrc + k + (size_t)128 * K_DIM,  lds + sb + 32768 + 8192 + t16);
    };
    auto stA1 = [&](int c) {
        const int sb = (c & 1) * 65536; const size_t k = (size_t)c * 64 + 32;
        GLOAD_LDS16(Asrc + k,                        lds + sb + 16384 + t16);
        GLOAD_LDS16(Asrc + k + (size_t)128 * K_DIM,  lds + sb + 16384 + 8192 + t16);
    };
    auto stB1 = [&](int c) {
        const int sb = (c & 1) * 65536; const size_t k = (size_t)c * 64 + 32;
        GLOAD_LDS16(Bsrc + k,                        lds + sb + 49152 + t16);
        GLOAD_LDS16(Bsrc + k + (size_t)128 * K_DIM,  lds + sb + 49152 + 8192 + t16);
    };

    // one K-tile = 4 phases, 2 barriers (after ph1 and after ph3)
    auto tile = [&](int c, bool st, bool tail) {
        const int buf = (c & 1) * 65536;
        bf16x8 afr[4], bfr[4];
        // ---- ph0: kk0, fr0-3 ----
        #pragma unroll
        for (int fc = 0; fc < 4; ++fc)
            bfr[fc] = *reinterpret_cast<const bf16x8*>(lds + buf + 32768 + boff[fc]);
        #pragma unroll
        for (int fr = 0; fr < 4; ++fr)
            afr[fr] = *reinterpret_cast<const bf16x8*>(lds + buf + aoff[fr]);
        if (st) stA0(c + 1);
        __builtin_amdgcn_s_setprio(1);
        #pragma unroll
        for (int fr = 0; fr < 4; ++fr)
            #pragma unroll
            for (int fc = 0; fc < 4; ++fc)
                acc[fr][fc] = __builtin_amdgcn_mfma_f32_16x16x32_bf16(
                    afr[fr], bfr[fc], acc[fr][fc], 0, 0, 0);
        __builtin_amdgcn_s_setprio(0);
        // ---- ph1: kk0, fr4-7 (bfr held; no barrier before) ----
        #pragma unroll
        for (int fr = 0; fr < 4; ++fr)
            afr[fr] = *reinterpret_cast<const bf16x8*>(lds + buf + aoff[fr + 4]);
        if (st) stB0(c + 1);
        __builtin_amdgcn_s_setprio(1);
        #pragma unroll
        for (int fr = 0; fr < 4; ++fr)
            #pragma unroll
            for (int fc = 0; fc < 4; ++fc)
                acc[fr + 4][fc] = __builtin_amdgcn_mfma_f32_16x16x32_bf16(
                    afr[fr], bfr[fc], acc[fr + 4][fc], 0, 0, 0);
        __builtin_amdgcn_s_setprio(0);
        // sync: retire A1,B1(c) (own loads) + cross-wave visibility
        if (tail) { WAIT_VM0(); } else { WAIT_VM4(); }
        __builtin_amdgcn_s_barrier();
        // ---- ph2: kk1, fr0-3 ----
        #pragma unroll
        for (int fc = 0; fc < 4; ++fc)
            bfr[fc] = *reinterpret_cast<const bf16x8*>(lds + buf + 49152 + boff[fc]);
        #pragma unroll
        for (int fr = 0; fr < 4; ++fr)
            afr[fr] = *reinterpret_cast<const bf16x8*>(lds + buf + 16384 + aoff[fr]);
        if (st) stA1(c + 1);
        __builtin_amdgcn_s_setprio(1);
        #pragma unroll
        for (int fr = 0; fr < 4; ++fr)
            #pragma unroll
            for (int fc = 0; fc < 4; ++fc)
                acc[fr][fc] = __builtin_amdgcn_mfma_f32_16x16x32_bf16(
                    afr[fr], bfr[fc], acc[fr][fc], 0, 0, 0);
        __builtin_amdgcn_s_setprio(0);
        // ---- ph3: kk1, fr4-7 (no barrier before) ----
        #pragma unroll
        for (int fr = 0; fr < 4; ++fr)
            afr[fr] = *reinterpret_cast<const bf16x8*>(lds + buf + 16384 + aoff[fr + 4]);
        if (st) stB1(c + 1);
        __builtin_amdgcn_s_setprio(1);
        #pragma unroll
        for (int fr = 0; fr < 4; ++fr)
            #pragma unroll
            for (int fc = 0; fc < 4; ++fc)
                acc[fr + 4][fc] = __builtin_amdgcn_mfma_f32_16x16x32_bf16(
                    afr[fr], bfr[fc], acc[fr + 4][fc], 0, 0, 0);
        __builtin_amdgcn_s_setprio(0);
        // sync: retire A0,B0(c+1) + cross-wave visibility (skip at tail)
        if (!tail) {
            WAIT_VM4();
            __builtin_amdgcn_s_barrier();
        }
    };

    // prologue: stage tile 0; retire front halves (back stays in flight)
    stA0(0); stB0(0); stA1(0); stB1(0);
    WAIT_VM4();
    __builtin_amdgcn_s_barrier();

    for (int c = 0; c <= 62; ++c)
        tile(c, true, false);
    tile(63, false, true);

    // epilogue: OUT = acc + bias (non-temporal: written once, never re-read)
    #pragma unroll
    for (int fc = 0; fc < 4; ++fc) {
        const int n    = n0 + wc * 64 + fc * 16 + l15;
        const float bv = BIAS[n];
        #pragma unroll
        for (int fr = 0; fr < 8; ++fr) {
            const int mb = m0 + wr * 128 + fr * 16 + (lhi << 2);
            #pragma unroll
            for (int t = 0; t < 4; ++t)
                __builtin_nontemporal_store(acc[fr][fc][t] + bv,
                    &OUT[(size_t)(mb + t) * N_DIM + n]);
        }
    }
}

// ---------------- Fallback: round-1 fused kernel ----------------
__global__ void __launch_bounds__(256) gptq_gemm_kernel(
    const float* __restrict__ X, const int* __restrict__ QW,
    const int* __restrict__ QZ, const float* __restrict__ SC,
    const float* __restrict__ BIAS, float* __restrict__ OUT)
{
    __shared__ __align__(16) unsigned char slds[32768];
    const int tid  = threadIdx.x;
    const int n0   = blockIdx.x * 128;
    const int m0   = blockIdx.y * 128;
    const int wave = tid >> 6;
    const int lane = tid & 63;
    const int wm   = (wave >> 1) * 64;
    const int wn   = (wave & 1) * 64;
    const int l15  = lane & 15;
    const int lhi  = lane >> 4;
    const int arow  = tid >> 4;
    const int acol4 = (tid & 15) << 2;
    const int bnl   = tid & 127;
    const int brb   = tid >> 7;
    const int col   = n0 + bnl;

    f32x4 acc[4][4] = {};
    for (int kt = 0; kt < K_DIM / 64; ++kt) {
        const int k0 = kt * 64;
        #pragma unroll
        for (int r8 = 0; r8 < 8; ++r8) {
            const int row = (r8 << 4) + arow;
            f32x4 v = *reinterpret_cast<const f32x4*>(
                X + (size_t)(m0 + row) * K_DIM + (k0 + acol4));
            u16x4 h;
            #pragma unroll
            for (int e = 0; e < 4; ++e) h[e] = f2bf(v[e]);
            const int bo = row * 128 + ((acol4 << 1) ^ ((row & 7) << 4));
            *reinterpret_cast<u16x4*>(slds + bo) = h;
        }
        {
            const int g    = k0 >> 7;
            const int zp   = (((unsigned)QZ[g * (N_DIM / 8) + (col >> 3)])
                              >> ((col & 7) << 2)) & 15;
            const float sc = SC[g * N_DIM + col];
            const float zs = (float)zp * sc;
            #pragma unroll
            for (int rb = 0; rb < 4; ++rb) {
                const int rl = (rb << 1) + brb;
                const unsigned qw =
                    (unsigned)QW[(size_t)((k0 >> 3) + rl) * N_DIM + col];
                u16x8 h;
                #pragma unroll
                for (int j = 0; j < 8; ++j) {
                    float w = (float)((qw >> (j << 2)) & 15u) * sc - zs;
                    h[j] = f2bf(w);
                }
                const int bo = 16384 + bnl * 128 + ((rl << 4) ^ ((bnl & 7) << 4));
                *reinterpret_cast<u16x8*>(slds + bo) = h;
            }
        }
        __syncthreads();
        #pragma unroll
        for (int kk = 0; kk < 2; ++kk) {
            bf16x8 afr[4], bfr[4];
            #pragma unroll
            for (int i = 0; i < 4; ++i) {
                const int row = wm + (i << 4) + l15;
                afr[i] = *reinterpret_cast<const bf16x8*>(
                    slds + row * 128 + (((kk << 6) + (lhi << 4)) ^ ((row & 7) << 4)));
            }
            #pragma unroll
            for (int j = 0; j < 4; ++j) {
                const int n = wn + (j << 4) + l15;
                bfr[j] = *reinterpret_cast<const bf16x8*>(
                    slds + 16384 + n * 128 + (((kk << 6) + (lhi << 4)) ^ ((n & 7) << 4)));
            }
            #pragma unroll
            for (int i = 0; i < 4; ++i)
                #pragma unroll
                for (int j = 0; j < 4; ++j)
                    acc[i][j] = __builtin_amdgcn_mfma_f32_16x16x32_bf16(
                        afr[i], bfr[j], acc[i][j], 0, 0, 0);
        }
        __syncthreads();
    }
    #pragma unroll
    for (int j = 0; j < 4; ++j) {
        const int n    = n0 + wn + (j << 4) + l15;
        const float bv = BIAS[n];
        #pragma unroll
        for (int i = 0; i < 4; ++i) {
            const int mb = m0 + wm + (i << 4) + (lhi << 2);
            #pragma unroll
            for (int t = 0; t < 4; ++t)
                OUT[(size_t)(mb + t) * N_DIM + n] = acc[i][j][t] + bv;
        }
    }
}

extern "C" void kernel_launch(void* const* d_in, const int* in_sizes, int n_in,
                              void* d_out, int out_size, void* d_ws, size_t ws_size,
                              hipStream_t stream) {
    const float* X  = (const float*)d_in[0];
    const int*   QW = (const int*)d_in[1];
    const int*   QZ = (const int*)d_in[2];
    const float* SC = (const float*)d_in[3];
    const float* BI = (const float*)d_in[4];
    float*      OUT = (float*)d_out;

    const size_t xbf_bytes = (size_t)M_DIM * K_DIM * 2;
    const size_t wt_bytes  = (size_t)N_DIM * K_DIM * 2;

    if (ws_size >= xbf_bytes + wt_bytes) {
        __hip_bfloat16* Xbf = (__hip_bfloat16*)d_ws;
        __hip_bfloat16* Wt  = (__hip_bfloat16*)((char*)d_ws + xbf_bytes);

        prep_kernel<<<DQ_BLOCKS + CVT_BLOCKS, 256, 0, stream>>>(
            X, QW, QZ, SC, Xbf, Wt);
        gemm_bf16_kernel<<<dim3((M_DIM / 256) * (N_DIM / 256)), 512, 131072, stream>>>(
            Xbf, Wt, BI, OUT);
    } else {
        gptq_gemm_kernel<<<dim3(N_DIM / 128, M_DIM / 128), 256, 0, stream>>>(
            X, QW, QZ, SC, BI, OUT);
    }
}